// Round 3
// baseline (16058.786 us; speedup 1.0000x reference)
//
#include <hip/hip_runtime.h>
#include <hip/hip_bf16.h>

#define SEQ   512
#define HID   1024
#define KTOT  2048
#define NBLK  256
#define NTHR  256
#define PADK  2056   // padded k-stride (elements) for LDS weight rows

typedef __attribute__((ext_vector_type(8))) short bf16x8;
typedef __attribute__((ext_vector_type(4))) float f32x4;
typedef __attribute__((ext_vector_type(2))) float f32x2;

struct Params {
  const float* x;        // [64][512][1024] f32
  const float* Wi[4];    // input-side weights  [1024][1024] f32, gates i,f,g,o
  const float* Wh[4];    // hidden-side weights [1024][1024] f32
  const float* bi[4];    // biases f32 [1024]
  const float* bh[4];
  float* out;            // d_out f32: doubles as h ping-pong [h0|h1]; final [h_T|c_T]
  unsigned* bar;         // d_ws: bar[0]=arrival counter, bar[64]=generation
};

__global__ __launch_bounds__(256) void init_ws(float* h0, unsigned* bar) {
  int i = blockIdx.x * blockDim.x + threadIdx.x;
  if (i < 65536) h0[i] = 0.0f;   // zero first half of d_out (h at t=0)
  if (i < 128) bar[i] = 0u;
}

__device__ __forceinline__ float sig_(float v)  { return 1.0f / (1.0f + __expf(-v)); }
__device__ __forceinline__ float tanh_(float v) { return 1.0f - 2.0f / (__expf(2.0f * v) + 1.0f); }

// f32 -> bf16 bits, round-to-nearest-even
__device__ __forceinline__ short f2b(float f) {
  unsigned u = __builtin_bit_cast(unsigned, f);
  u += 0x7FFFu + ((u >> 16) & 1u);
  return (short)(u >> 16);
}

// load 8 consecutive f32, convert to bf16x8 fragment
__device__ __forceinline__ bf16x8 cvt8(const float* p) {
  f32x4 a = *(const f32x4*)p;
  f32x4 b = *(const f32x4*)(p + 4);
  bf16x8 r;
  r[0] = f2b(a[0]); r[1] = f2b(a[1]); r[2] = f2b(a[2]); r[3] = f2b(a[3]);
  r[4] = f2b(b[0]); r[5] = f2b(b[1]); r[6] = f2b(b[2]); r[7] = f2b(b[3]);
  return r;
}

// Grid barrier: monotonic counter + generation flag, agent scope, fenced for
// cross-XCD visibility of plain h loads/stores (G16).
__device__ __forceinline__ void gbar(unsigned* bar, int tid, unsigned step) {
  __syncthreads();                               // all threads' h-stores issued+drained
  if (tid == 0) {
    __threadfence();                             // flush to coherence point
    unsigned prev = __hip_atomic_fetch_add(&bar[0], 1u, __ATOMIC_ACQ_REL,
                                           __HIP_MEMORY_SCOPE_AGENT);
    if (prev == step * NBLK + (NBLK - 1)) {
      __hip_atomic_store(&bar[64], step + 1, __ATOMIC_RELEASE,
                         __HIP_MEMORY_SCOPE_AGENT);
    } else {
      int polls = 0;
      while (__hip_atomic_load(&bar[64], __ATOMIC_ACQUIRE,
                               __HIP_MEMORY_SCOPE_AGENT) < step + 1) {
        __builtin_amdgcn_s_sleep(8);
        if (++polls > (1 << 22)) break;          // hang insurance
      }
    }
    __threadfence();                             // invalidate before h-reads
  }
  __syncthreads();
}

// LDS: bls[32][PADK] bf16 weight slab (row n = interleaved gate-col 4j+g),
//      gparts[2][32][32] f32, cst[32][8] f32, bias_s[32] f32   (140928 B)
__global__ __launch_bounds__(NTHR, 1) void lstm_persistent(Params p) {
  extern __shared__ char smem[];
  short* bls    = (short*)smem;
  float* gparts = (float*)(smem + 32 * PADK * 2);          // +131584
  float* cst    = (float*)(smem + 32 * PADK * 2 + 8192);   // +139776
  float* bias_s = (float*)(smem + 32 * PADK * 2 + 9216);   // +140800

  const int tid  = threadIdx.x;
  const int bid  = blockIdx.x;
  const int cg   = bid & 127;      // column group: gate cols [32cg, 32cg+32)
  const int mh   = bid >> 7;       // batch half: rows [32mh, 32mh+32)
  const int r0   = mh * 32;
  const int j0   = cg * 8;         // hidden cols [j0, j0+8)

  float* h0 = p.out;               // first half of d_out (f32 h buffer)
  float* h1 = p.out + 65536;       // second half

  // ---- one-time: stage weight slab into LDS (interleaved col = 4j+g) ----
  {
    const int g    = tid & 3;
    const int krow = tid >> 2;     // 0..63
    const float* wi = p.Wi[g];
    const float* wh = p.Wh[g];
    for (int kb = 0; kb < KTOT; kb += 64) {
      int k = kb + krow;
      const float* src = (k < HID) ? (wi + (size_t)k * HID + j0)
                                   : (wh + (size_t)(k - HID) * HID + j0);
      f32x4 va = *(const f32x4*)src;
      f32x4 vb = *(const f32x4*)(src + 4);
      #pragma unroll
      for (int jj = 0; jj < 4; ++jj) {
        bls[(4 * jj + g) * PADK + k]       = f2b(va[jj]);
        bls[(4 * (jj + 4) + g) * PADK + k] = f2b(vb[jj]);
      }
    }
  }
  if (tid < 32) {
    int g = tid & 3, j = j0 + (tid >> 2);
    bias_s[tid] = p.bi[g][j] + p.bh[g][j];
  }
  if (tid < 128) { cst[2 * tid] = 0.0f; cst[2 * tid + 1] = 0.0f; }
  __syncthreads();

  const int lane  = tid & 63;
  const int wv    = tid >> 6;     // 4 waves
  const int kside = wv >> 1;      // 0: x-part of K, 1: h-part
  const int mt    = wv & 1;       // M-tile within block
  const int m16   = lane & 15;
  const int quad  = lane >> 4;
  const int rm    = r0 + mt * 16 + m16;   // global batch row for A-frag
  const short* bp0 = bls + m16 * PADK;            // B tile nt=0 (n = lane&15)
  const short* bp1 = bls + (16 + m16) * PADK;     // B tile nt=1
  const float* xrow = p.x + (size_t)rm * SEQ * HID;

  float cfin0 = 0.0f, cfin1 = 0.0f;

  for (int t = 0; t < SEQ; ++t) {
    const float* hread = (t & 1) ? h1 : h0;
    float* hwrite      = (t & 1) ? h0 : h1;

    f32x4 acc0 = {0.f, 0.f, 0.f, 0.f};
    f32x4 acc1 = {0.f, 0.f, 0.f, 0.f};

    const float* ab = (kside == 0) ? (xrow + (size_t)t * HID + quad * 8)
                                   : (hread + (size_t)rm * HID + quad * 8);
    const int boff = kside ? 1024 : 0;
    #pragma unroll 4
    for (int ki = 0; ki < 32; ++ki) {
      bf16x8 a  = cvt8(ab + ki * 32);
      bf16x8 b0 = *(const bf16x8*)(bp0 + boff + ki * 32 + quad * 8);
      bf16x8 b1 = *(const bf16x8*)(bp1 + boff + ki * 32 + quad * 8);
      acc0 = __builtin_amdgcn_mfma_f32_16x16x32_bf16(a, b0, acc0, 0, 0, 0);
      acc1 = __builtin_amdgcn_mfma_f32_16x16x32_bf16(a, b1, acc1, 0, 0, 0);
    }

    // C layout: col=lane&15, row=quad*4+reg (guide §3, HW-verified)
    {
      float* gp = gparts + kside * 1024;
      int rl = mt * 16 + quad * 4;
      #pragma unroll
      for (int r = 0; r < 4; ++r) {
        gp[(rl + r) * 32 + m16]      = acc0[r];
        gp[(rl + r) * 32 + 16 + m16] = acc1[r];
      }
    }
    __syncthreads();

    // ---- elementwise cell update: 32 rows x 4 col-pairs, 128 threads ----
    if (tid < 128) {
      int rl = tid >> 2;          // 0..31
      int jp = tid & 3;           // hidden cols j0+2jp, j0+2jp+1
      int base = rl * 32 + jp * 8;
      f32x4 ga = *(const f32x4*)(gparts + base);
      f32x4 gb = *(const f32x4*)(gparts + base + 4);
      f32x4 ha = *(const f32x4*)(gparts + 1024 + base);
      f32x4 hb = *(const f32x4*)(gparts + 1024 + base + 4);
      f32x4 ba = *(const f32x4*)(bias_s + jp * 8);
      f32x4 bb = *(const f32x4*)(bias_s + jp * 8 + 4);

      float i0 = sig_(ga[0] + ha[0] + ba[0]);
      float f0 = sig_(ga[1] + ha[1] + ba[1]);
      float g0 = tanh_(ga[2] + ha[2] + ba[2]);
      float o0 = sig_(ga[3] + ha[3] + ba[3]);
      float i1 = sig_(gb[0] + hb[0] + bb[0]);
      float f1 = sig_(gb[1] + hb[1] + bb[1]);
      float g1 = tanh_(gb[2] + hb[2] + bb[2]);
      float o1 = sig_(gb[3] + hb[3] + bb[3]);

      int ci = rl * 8 + jp * 2;
      float c0 = f0 * cst[ci]     + i0 * g0;
      float c1 = f1 * cst[ci + 1] + i1 * g1;
      cst[ci] = c0; cst[ci + 1] = c1;
      float h0v = o0 * tanh_(c0);
      float h1v = o1 * tanh_(c1);
      if (t == SEQ - 1) { cfin0 = c0; cfin1 = c1; }

      size_t off = (size_t)(r0 + rl) * HID + j0 + jp * 2;
      f32x2 hv = {h0v, h1v};
      *(f32x2*)(hwrite + off) = hv;    // t=SEQ-1 parity lands h_T in first half
    }

    gbar(p.bar, tid, (unsigned)t);
  }

  // After final barrier no block reads h1 anymore -> write c_T over second half.
  if (tid < 128) {
    int rl = tid >> 2, jp = tid & 3;
    size_t off = (size_t)(r0 + rl) * HID + j0 + jp * 2;
    f32x2 cv = {cfin0, cfin1};
    *(f32x2*)(p.out + 65536 + off) = cv;
  }
}

extern "C" void kernel_launch(void* const* d_in, const int* in_sizes, int n_in,
                              void* d_out, int out_size, void* d_ws, size_t ws_size,
                              hipStream_t stream) {
  // d_in: 0=x, 1..4 = W_ii,W_fi,W_gi,W_oi, 5..8 = W_ih,W_fh,W_gh,W_oh,
  //       9..16 = b_ii,b_ih,b_fi,b_fh,b_gi,b_gh,b_oi,b_oh   (ALL float32)
  Params prm;
  prm.x = (const float*)d_in[0];
  for (int g = 0; g < 4; ++g) {
    prm.Wi[g] = (const float*)d_in[1 + g];
    prm.Wh[g] = (const float*)d_in[5 + g];
    prm.bi[g] = (const float*)d_in[9 + 2 * g];
    prm.bh[g] = (const float*)d_in[10 + 2 * g];
  }
  prm.out = (float*)d_out;
  prm.bar = (unsigned*)d_ws;   // 512 B of barrier state only

  const int smem_bytes = 32 * PADK * 2 + 8192 + 1024 + 128;  // 140928
  hipFuncSetAttribute((const void*)lstm_persistent,
                      hipFuncAttributeMaxDynamicSharedMemorySize, smem_bytes);

  init_ws<<<256, 256, 0, stream>>>((float*)d_out, (unsigned*)d_ws);
  lstm_persistent<<<NBLK, NTHR, smem_bytes, stream>>>(prm);
}

// Round 4
// 9922.105 us; speedup vs baseline: 1.6185x; 1.6185x over previous
//
#include <hip/hip_runtime.h>
#include <hip/hip_bf16.h>

#define SEQ   512
#define HID   1024
#define NBLK  256
#define NTHR  256
#define PADK  2056   // LDS weight row stride (shorts); 4112 B, 16B-aligned
#define GPS   36     // gparts row stride (dwords) — breaks stride-32 conflicts

typedef __attribute__((ext_vector_type(8))) short bf16x8;
typedef __attribute__((ext_vector_type(4))) float f32x4;
typedef __attribute__((ext_vector_type(2))) float f32x2;

struct Params {
  const float* x;        // [64][512][1024] f32
  const float* Wi[4];    // [1024][1024] f32, gates i,f,g,o
  const float* Wh[4];
  const float* bi[4];
  const float* bh[4];
  float* out;            // f32 [h_T | c_T]; TIER0 also uses halves as h ping-pong
  const short* xbf;      // TIER FULL: x pre-converted to bf16
  short* hb0;            // TIER FULL: bf16 h ping-pong
  short* hb1;
  unsigned* arrive;      // [256] slots, stride 16 u32 (64B padded)
  unsigned* gen;         // generation flag (own cacheline)
};

__device__ __forceinline__ float sig_(float v)  { return 1.0f / (1.0f + __expf(-v)); }
__device__ __forceinline__ float tanh_(float v) { return 1.0f - 2.0f / (__expf(2.0f * v) + 1.0f); }

__device__ __forceinline__ short f2b(float f) {   // f32 -> bf16 RNE
  unsigned u = __builtin_bit_cast(unsigned, f);
  u += 0x7FFFu + ((u >> 16) & 1u);
  return (short)(u >> 16);
}
__device__ __forceinline__ bf16x8 cvt8(const float* p) {
  f32x4 a = *(const f32x4*)p;
  f32x4 b = *(const f32x4*)(p + 4);
  bf16x8 r;
  r[0] = f2b(a[0]); r[1] = f2b(a[1]); r[2] = f2b(a[2]); r[3] = f2b(a[3]);
  r[4] = f2b(b[0]); r[5] = f2b(b[1]); r[6] = f2b(b[2]); r[7] = f2b(b[3]);
  return r;
}

__global__ __launch_bounds__(256) void init_ws(unsigned* bar, unsigned* hzero, int hn) {
  int i = blockIdx.x * blockDim.x + threadIdx.x;
  if (i < 4161) bar[i] = 0u;              // arrival slots + gen (bar[4096])
  if (i < hn) hzero[i] = 0u;              // zero h(t=0) buffer
}

__global__ __launch_bounds__(256) void cvt_x(const float* __restrict__ x,
                                             short* __restrict__ xb) {
  size_t i = ((size_t)blockIdx.x * 256 + threadIdx.x) * 8;
  *(bf16x8*)(xb + i) = cvt8(x + i);
}

// Barrier v2: distributed arrival slots (no shared RMW), block0 aggregates.
__device__ __forceinline__ void gbar(unsigned* arrive, unsigned* gen,
                                     int tid, int bid, unsigned tgt) {
  __syncthreads();                               // all h-stores drained (vmcnt)
  if (bid == 0) {
    if (tid != 0) {
      int polls = 0;
      while (__hip_atomic_load(&arrive[tid * 16], __ATOMIC_RELAXED,
                               __HIP_MEMORY_SCOPE_AGENT) < tgt) {
        __builtin_amdgcn_s_sleep(1);
        if (++polls > (1 << 20)) break;          // hang insurance
      }
    }
    __syncthreads();
    if (tid == 0) {
      __threadfence();                           // order block0 h-stores + cache inv
      __hip_atomic_store(gen, tgt, __ATOMIC_RELEASE, __HIP_MEMORY_SCOPE_AGENT);
    }
    __syncthreads();
  } else {
    if (tid == 0) {
      __threadfence();                           // release this block's h-stores
      __hip_atomic_store(&arrive[bid * 16], tgt, __ATOMIC_RELEASE,
                         __HIP_MEMORY_SCOPE_AGENT);
      int polls = 0;
      while (__hip_atomic_load(gen, __ATOMIC_RELAXED,
                               __HIP_MEMORY_SCOPE_AGENT) < tgt) {
        __builtin_amdgcn_s_sleep(1);
        if (++polls > (1 << 20)) break;
      }
      __threadfence();                           // acquire: invalidate before h-reads
    }
    __syncthreads();
  }
}

// LDS: bls[32][PADK] bf16 (row = interleaved gate-col 4*jl+g), 131584 B
//      gparts[4][32][GPS] f32 (4 K-slices)                     18432 B
//      cst[32][8] f32                                           1024 B
//      bias_s[32] f32                                            128 B   = 151168 B
template <bool FULL>
__global__ __launch_bounds__(NTHR, 1) void lstm_persistent(Params p) {
  extern __shared__ char smem[];
  short* bls    = (short*)smem;
  float* gparts = (float*)(smem + 131584);
  float* cst    = (float*)(smem + 131584 + 18432);
  float* bias_s = (float*)(smem + 131584 + 18432 + 1024);

  const int tid = threadIdx.x;
  const int bid = blockIdx.x;
  const int cg  = bid & 127;       // gate-col group: cols [32cg, 32cg+32)
  const int mh  = bid >> 7;        // batch half
  const int r0  = mh * 32;
  const int j0  = cg * 8;          // hidden cols [j0, j0+8)

  // ---- one-time: stage bf16 weight slab, interleaved col = 4*jl + g ----
  {
    const int g    = tid & 3;
    const int krow = tid >> 2;     // 0..63
    const float* wi = p.Wi[g];
    const float* wh = p.Wh[g];
    for (int kb = 0; kb < 2048; kb += 64) {
      int k = kb + krow;
      const float* src = (k < HID) ? (wi + (size_t)k * HID + j0)
                                   : (wh + (size_t)(k - HID) * HID + j0);
      f32x4 va = *(const f32x4*)src;
      f32x4 vb = *(const f32x4*)(src + 4);
      #pragma unroll
      for (int jj = 0; jj < 4; ++jj) {
        bls[(4 * jj + g) * PADK + k]       = f2b(va[jj]);
        bls[(4 * (jj + 4) + g) * PADK + k] = f2b(vb[jj]);
      }
    }
  }
  if (tid < 32) {
    int g = tid & 3, j = j0 + (tid >> 2);
    bias_s[tid] = p.bi[g][j] + p.bh[g][j];
  }
  if (tid < 128) { cst[2 * tid] = 0.0f; cst[2 * tid + 1] = 0.0f; }
  __syncthreads();

  const int lane = tid & 63;
  const int ksl  = tid >> 6;       // K-slice 0..3 (512 each); 0,1 = x-part, 2,3 = h-part
  const int m16  = lane & 15;
  const int quad = lane >> 4;
  const size_t rm0 = (size_t)(r0 + m16);
  const size_t rm1 = (size_t)(r0 + 16 + m16);
  const short* bB0 = bls + (size_t)m16 * PADK + ksl * 512 + quad * 8;        // nt=0
  const short* bB1 = bls + (size_t)(16 + m16) * PADK + ksl * 512 + quad * 8; // nt=1

  float cfin0 = 0.0f, cfin1 = 0.0f;

  for (int t = 0; t < SEQ; ++t) {
    f32x4 acc00 = {0,0,0,0}, acc01 = {0,0,0,0};
    f32x4 acc10 = {0,0,0,0}, acc11 = {0,0,0,0};

    if constexpr (FULL) {
      const short *pa0, *pa1;
      if (ksl < 2) {
        const short* xb = p.xbf + ksl * 512 + quad * 8 + (size_t)t * HID;
        pa0 = xb + rm0 * (SEQ * HID);
        pa1 = xb + rm1 * (SEQ * HID);
      } else {
        const short* hr = ((t & 1) ? p.hb1 : p.hb0) + (ksl - 2) * 512 + quad * 8;
        pa0 = hr + rm0 * HID;
        pa1 = hr + rm1 * HID;
      }
      #pragma unroll 4
      for (int ki = 0; ki < 16; ++ki) {
        bf16x8 a0 = *(const bf16x8*)(pa0 + ki * 32);
        bf16x8 a1 = *(const bf16x8*)(pa1 + ki * 32);
        bf16x8 b0 = *(const bf16x8*)(bB0 + ki * 32);
        bf16x8 b1 = *(const bf16x8*)(bB1 + ki * 32);
        acc00 = __builtin_amdgcn_mfma_f32_16x16x32_bf16(a0, b0, acc00, 0, 0, 0);
        acc01 = __builtin_amdgcn_mfma_f32_16x16x32_bf16(a0, b1, acc01, 0, 0, 0);
        acc10 = __builtin_amdgcn_mfma_f32_16x16x32_bf16(a1, b0, acc10, 0, 0, 0);
        acc11 = __builtin_amdgcn_mfma_f32_16x16x32_bf16(a1, b1, acc11, 0, 0, 0);
      }
    } else {
      const float *fa0, *fa1;
      if (ksl < 2) {
        const float* xb = p.x + ksl * 512 + quad * 8 + (size_t)t * HID;
        fa0 = xb + rm0 * (SEQ * HID);
        fa1 = xb + rm1 * (SEQ * HID);
      } else {
        const float* hr = (p.out + ((t & 1) ? 65536 : 0)) + (ksl - 2) * 512 + quad * 8;
        fa0 = hr + rm0 * HID;
        fa1 = hr + rm1 * HID;
      }
      #pragma unroll 2
      for (int ki = 0; ki < 16; ++ki) {
        bf16x8 a0 = cvt8(fa0 + ki * 32);
        bf16x8 a1 = cvt8(fa1 + ki * 32);
        bf16x8 b0 = *(const bf16x8*)(bB0 + ki * 32);
        bf16x8 b1 = *(const bf16x8*)(bB1 + ki * 32);
        acc00 = __builtin_amdgcn_mfma_f32_16x16x32_bf16(a0, b0, acc00, 0, 0, 0);
        acc01 = __builtin_amdgcn_mfma_f32_16x16x32_bf16(a0, b1, acc01, 0, 0, 0);
        acc10 = __builtin_amdgcn_mfma_f32_16x16x32_bf16(a1, b0, acc10, 0, 0, 0);
        acc11 = __builtin_amdgcn_mfma_f32_16x16x32_bf16(a1, b1, acc11, 0, 0, 0);
      }
    }

    // C layout: col = lane&15, row = quad*4 + reg (HW-verified round 3)
    {
      float* gp = gparts + ksl * (32 * GPS);
      #pragma unroll
      for (int r = 0; r < 4; ++r) {
        gp[(quad * 4 + r) * GPS + m16]           = acc00[r];
        gp[(quad * 4 + r) * GPS + 16 + m16]      = acc01[r];
        gp[(16 + quad * 4 + r) * GPS + m16]      = acc10[r];
        gp[(16 + quad * 4 + r) * GPS + 16 + m16] = acc11[r];
      }
    }
    __syncthreads();

    // ---- cell update: 32 rows x 4 col-pairs (128 threads) ----
    if (tid < 128) {
      int rl = tid >> 2, jp = tid & 3;
      f32x4 ga = {0,0,0,0}, gb = {0,0,0,0};
      #pragma unroll
      for (int s = 0; s < 4; ++s) {
        const float* gp = gparts + s * (32 * GPS) + rl * GPS + jp * 8;
        ga += *(const f32x4*)gp;
        gb += *(const f32x4*)(gp + 4);
      }
      f32x4 ba = *(const f32x4*)(bias_s + jp * 8);
      f32x4 bb = *(const f32x4*)(bias_s + jp * 8 + 4);

      float i0 = sig_(ga[0] + ba[0]);
      float f0 = sig_(ga[1] + ba[1]);
      float g0 = tanh_(ga[2] + ba[2]);
      float o0 = sig_(ga[3] + ba[3]);
      float i1 = sig_(gb[0] + bb[0]);
      float f1 = sig_(gb[1] + bb[1]);
      float g1 = tanh_(gb[2] + bb[2]);
      float o1 = sig_(gb[3] + bb[3]);

      int ci = rl * 8 + jp * 2;
      float c0 = f0 * cst[ci]     + i0 * g0;
      float c1 = f1 * cst[ci + 1] + i1 * g1;
      cst[ci] = c0; cst[ci + 1] = c1;
      float h0v = o0 * tanh_(c0);
      float h1v = o1 * tanh_(c1);

      size_t off = (size_t)(r0 + rl) * HID + j0 + jp * 2;
      if constexpr (FULL) {
        short* hw = (t & 1) ? p.hb0 : p.hb1;
        unsigned u = (unsigned)(unsigned short)f2b(h0v) |
                     ((unsigned)(unsigned short)f2b(h1v) << 16);
        *(unsigned*)(hw + off) = u;
        if (t == SEQ - 1) {
          f32x2 hv = {h0v, h1v}; *(f32x2*)(p.out + off) = hv;
          f32x2 cv = {c0, c1};   *(f32x2*)(p.out + 65536 + off) = cv;
        }
      } else {
        float* hw = p.out + ((t & 1) ? 0 : 65536);
        f32x2 hv = {h0v, h1v};
        *(f32x2*)(hw + off) = hv;          // t=511 parity lands h_T in first half
        if (t == SEQ - 1) { cfin0 = c0; cfin1 = c1; }
      }
    }

    gbar(p.arrive, p.gen, tid, bid, (unsigned)(t + 1));
  }

  if constexpr (!FULL) {                   // c_T over second half, post final barrier
    if (tid < 128) {
      int rl = tid >> 2, jp = tid & 3;
      size_t off = (size_t)(r0 + rl) * HID + j0 + jp * 2;
      f32x2 cv = {cfin0, cfin1};
      *(f32x2*)(p.out + 65536 + off) = cv;
    }
  }
}

extern "C" void kernel_launch(void* const* d_in, const int* in_sizes, int n_in,
                              void* d_out, int out_size, void* d_ws, size_t ws_size,
                              hipStream_t stream) {
  Params prm;
  prm.x = (const float*)d_in[0];
  for (int g = 0; g < 4; ++g) {
    prm.Wi[g] = (const float*)d_in[1 + g];
    prm.Wh[g] = (const float*)d_in[5 + g];
    prm.bi[g] = (const float*)d_in[9 + 2 * g];
    prm.bh[g] = (const float*)d_in[10 + 2 * g];
  }
  prm.out    = (float*)d_out;
  prm.arrive = (unsigned*)d_ws;
  prm.gen    = prm.arrive + 4096;          // byte offset 16384, own line
  prm.xbf = nullptr; prm.hb0 = nullptr; prm.hb1 = nullptr;

  const size_t need_full = 32768 + 67108864 + 2 * 131072;   // ~67.4 MB
  const bool full = ws_size >= need_full;
  if (full) {
    prm.xbf = (const short*)((char*)d_ws + 32768);
    prm.hb0 = (short*)((char*)d_ws + 32768 + 67108864);
    prm.hb1 = prm.hb0 + 65536;
  }

  const int smem_bytes = 131584 + 18432 + 1024 + 128;   // 151168
  hipFuncSetAttribute((const void*)lstm_persistent<true>,
                      hipFuncAttributeMaxDynamicSharedMemorySize, smem_bytes);
  hipFuncSetAttribute((const void*)lstm_persistent<false>,
                      hipFuncAttributeMaxDynamicSharedMemorySize, smem_bytes);

  if (full) {
    init_ws<<<256, 256, 0, stream>>>((unsigned*)d_ws, (unsigned*)prm.hb0, 32768);
    cvt_x<<<16384, 256, 0, stream>>>(prm.x, (short*)prm.xbf);
    lstm_persistent<true><<<NBLK, NTHR, smem_bytes, stream>>>(prm);
  } else {
    init_ws<<<256, 256, 0, stream>>>((unsigned*)d_ws, (unsigned*)d_out, 65536);
    lstm_persistent<false><<<NBLK, NTHR, smem_bytes, stream>>>(prm);
  }
}

// Round 5
// 4189.482 us; speedup vs baseline: 3.8331x; 2.3683x over previous
//
#include <hip/hip_runtime.h>
#include <hip/hip_bf16.h>

#define SEQ   512
#define HID   1024
#define NBLK  256
#define NTHR  256
#define PADK  2056   // LDS weight row stride (shorts); 4112 B, 16B-aligned
#define GPS   36     // gparts row stride (dwords) — breaks stride-32 conflicts

typedef __attribute__((ext_vector_type(8))) short bf16x8;
typedef __attribute__((ext_vector_type(4))) float f32x4;
typedef __attribute__((ext_vector_type(2))) float f32x2;

struct Params {
  const float* x;        // [64][512][1024] f32
  const float* Wi[4];    // [1024][1024] f32, gates i,f,g,o
  const float* Wh[4];
  const float* bi[4];
  const float* bh[4];
  float* out;            // f32 [h_T | c_T]; fallback tier also uses halves as h ping-pong
  const short* xbf;      // FULL: x pre-converted to bf16
  short* hb0;            // FULL: bf16 h ping-pong (accessed sc1/IF-coherent)
  short* hb1;
  unsigned* arrive;      // [256] slots, stride 32 u32 (128 B padded)
  unsigned* gen;         // generation flag (own line, = arrive+8192)
};

__device__ __forceinline__ float sig_(float v)  { return 1.0f / (1.0f + __expf(-v)); }
__device__ __forceinline__ float tanh_(float v) { return 1.0f - 2.0f / (__expf(2.0f * v) + 1.0f); }

__device__ __forceinline__ short f2b(float f) {   // f32 -> bf16 RNE
  unsigned u = __builtin_bit_cast(unsigned, f);
  u += 0x7FFFu + ((u >> 16) & 1u);
  return (short)(u >> 16);
}
__device__ __forceinline__ bf16x8 cvt8(const float* p) {
  f32x4 a = *(const f32x4*)p;
  f32x4 b = *(const f32x4*)(p + 4);
  bf16x8 r;
  r[0] = f2b(a[0]); r[1] = f2b(a[1]); r[2] = f2b(a[2]); r[3] = f2b(a[3]);
  r[4] = f2b(b[0]); r[5] = f2b(b[1]); r[6] = f2b(b[2]); r[7] = f2b(b[3]);
  return r;
}

// 16B load bypassing L1/L2 (device-coherent, served by Infinity Cache).
// Caller MUST batch these then execute wait_vm0() + launder before use.
__device__ __forceinline__ bf16x8 ld16_sc1(const short* p) {
  bf16x8 r;
  asm volatile("global_load_dwordx4 %0, %1, off sc1" : "=v"(r) : "v"(p));
  return r;
}
__device__ __forceinline__ void wait_vm0() {
  asm volatile("s_waitcnt vmcnt(0)" ::: "memory");
}

__global__ __launch_bounds__(256) void init_ws(unsigned* bar, unsigned* hzero, int hn) {
  int i = blockIdx.x * blockDim.x + threadIdx.x;
  if (i < 8448) bar[i] = 0u;              // arrive slots (8192) + gen + pad
  if (i < hn) hzero[i] = 0u;              // zero h(t=0) buffer
}

__global__ __launch_bounds__(256) void cvt_x(const float* __restrict__ x,
                                             short* __restrict__ xb) {
  size_t i = ((size_t)blockIdx.x * 256 + threadIdx.x) * 8;
  *(bf16x8*)(xb + i) = cvt8(x + i);
}

// ---- fallback-tier barrier (round-4 style, fence-based; correctness only) ----
__device__ __forceinline__ void gbar_fence(unsigned* arrive, unsigned* gen,
                                           int tid, int bid, unsigned tgt) {
  __syncthreads();
  if (bid == 0) {
    if (tid != 0) {
      int polls = 0;
      while (__hip_atomic_load(&arrive[tid * 32], __ATOMIC_RELAXED,
                               __HIP_MEMORY_SCOPE_AGENT) < tgt) {
        __builtin_amdgcn_s_sleep(1);
        if (++polls > (1 << 22)) break;
      }
    }
    __syncthreads();
    if (tid == 0) {
      __threadfence();
      __hip_atomic_store(gen, tgt, __ATOMIC_RELEASE, __HIP_MEMORY_SCOPE_AGENT);
    }
    __syncthreads();
  } else {
    if (tid == 0) {
      __threadfence();
      __hip_atomic_store(&arrive[bid * 32], tgt, __ATOMIC_RELEASE,
                         __HIP_MEMORY_SCOPE_AGENT);
      int polls = 0;
      while (__hip_atomic_load(gen, __ATOMIC_RELAXED,
                               __HIP_MEMORY_SCOPE_AGENT) < tgt) {
        __builtin_amdgcn_s_sleep(1);
        if (++polls > (1 << 22)) break;
      }
      __threadfence();
    }
    __syncthreads();
  }
}

// LDS: bls[32][PADK] bf16 (row = interleaved gate-col 4*jl+g), 131584 B
//      gparts[4][32][GPS] f32, cst[32][8] f32, bias_s[32] f32    = 151168 B
template <bool FULL>
__global__ __launch_bounds__(NTHR, 1) void lstm_persistent(Params p) {
  extern __shared__ char smem[];
  short* bls    = (short*)smem;
  float* gparts = (float*)(smem + 131584);
  float* cst    = (float*)(smem + 131584 + 18432);
  float* bias_s = (float*)(smem + 131584 + 18432 + 1024);

  const int tid = threadIdx.x;
  const int bid = blockIdx.x;
  const int cg  = bid & 127;       // gate-col group: cols [32cg, 32cg+32)
  const int mh  = bid >> 7;        // batch half
  const int r0  = mh * 32;
  const int j0  = cg * 8;          // hidden cols [j0, j0+8)

  // ---- one-time: stage bf16 weight slab, interleaved col = 4*jl + g ----
  {
    const int g    = tid & 3;
    const int krow = tid >> 2;     // 0..63
    const float* wi = p.Wi[g];
    const float* wh = p.Wh[g];
    for (int kb = 0; kb < 2048; kb += 64) {
      int k = kb + krow;
      const float* src = (k < HID) ? (wi + (size_t)k * HID + j0)
                                   : (wh + (size_t)(k - HID) * HID + j0);
      f32x4 va = *(const f32x4*)src;
      f32x4 vb = *(const f32x4*)(src + 4);
      #pragma unroll
      for (int jj = 0; jj < 4; ++jj) {
        bls[(4 * jj + g) * PADK + k]       = f2b(va[jj]);
        bls[(4 * (jj + 4) + g) * PADK + k] = f2b(vb[jj]);
      }
    }
  }
  if (tid < 32) {
    int g = tid & 3, j = j0 + (tid >> 2);
    bias_s[tid] = p.bi[g][j] + p.bh[g][j];
  }
  if (tid < 128) { cst[2 * tid] = 0.0f; cst[2 * tid + 1] = 0.0f; }
  __syncthreads();

  const int lane = tid & 63;
  const int ksl  = tid >> 6;       // K-slice 0..3; 0,1 = x-part, 2,3 = h-part
  const int m16  = lane & 15;
  const int quad = lane >> 4;
  const size_t rm0 = (size_t)(r0 + m16);
  const size_t rm1 = (size_t)(r0 + 16 + m16);
  const short* bB0 = bls + (size_t)m16 * PADK + ksl * 512 + quad * 8;        // nt=0
  const short* bB1 = bls + (size_t)(16 + m16) * PADK + ksl * 512 + quad * 8; // nt=1

  float cfin0 = 0.0f, cfin1 = 0.0f;

  for (int t = 0; t < SEQ; ++t) {
    f32x4 acc00 = {0,0,0,0}, acc01 = {0,0,0,0};
    f32x4 acc10 = {0,0,0,0}, acc11 = {0,0,0,0};

    if constexpr (FULL) {
      if (ksl < 2) {
        // x-part: normal cached loads (L2 stays warm — no invalidates anywhere)
        const short* xb = p.xbf + ksl * 512 + quad * 8 + (size_t)t * HID;
        const short* pa0 = xb + rm0 * (SEQ * HID);
        const short* pa1 = xb + rm1 * (SEQ * HID);
        #pragma unroll 4
        for (int ki = 0; ki < 16; ++ki) {
          bf16x8 a0 = *(const bf16x8*)(pa0 + ki * 32);
          bf16x8 a1 = *(const bf16x8*)(pa1 + ki * 32);
          bf16x8 b0 = *(const bf16x8*)(bB0 + ki * 32);
          bf16x8 b1 = *(const bf16x8*)(bB1 + ki * 32);
          acc00 = __builtin_amdgcn_mfma_f32_16x16x32_bf16(a0, b0, acc00, 0, 0, 0);
          acc01 = __builtin_amdgcn_mfma_f32_16x16x32_bf16(a0, b1, acc01, 0, 0, 0);
          acc10 = __builtin_amdgcn_mfma_f32_16x16x32_bf16(a1, b0, acc10, 0, 0, 0);
          acc11 = __builtin_amdgcn_mfma_f32_16x16x32_bf16(a1, b1, acc11, 0, 0, 0);
        }
      } else {
        // h-part: IF-coherent sc1 loads, batched 32-deep, single vmcnt wait
        const short* hr = ((t & 1) ? p.hb1 : p.hb0) + (ksl - 2) * 512 + quad * 8;
        const short* pa0 = hr + rm0 * HID;
        const short* pa1 = hr + rm1 * HID;
        bf16x8 A0[16], A1[16];
        #pragma unroll
        for (int ki = 0; ki < 16; ++ki) {
          A0[ki] = ld16_sc1(pa0 + ki * 32);
          A1[ki] = ld16_sc1(pa1 + ki * 32);
        }
        wait_vm0();
        #pragma unroll
        for (int ki = 0; ki < 16; ++ki) {   // launder: pin MFMAs after the wait
          asm volatile("" : "+v"(A0[ki]));
          asm volatile("" : "+v"(A1[ki]));
        }
        #pragma unroll
        for (int ki = 0; ki < 16; ++ki) {
          bf16x8 b0 = *(const bf16x8*)(bB0 + ki * 32);
          bf16x8 b1 = *(const bf16x8*)(bB1 + ki * 32);
          acc00 = __builtin_amdgcn_mfma_f32_16x16x32_bf16(A0[ki], b0, acc00, 0, 0, 0);
          acc01 = __builtin_amdgcn_mfma_f32_16x16x32_bf16(A0[ki], b1, acc01, 0, 0, 0);
          acc10 = __builtin_amdgcn_mfma_f32_16x16x32_bf16(A1[ki], b0, acc10, 0, 0, 0);
          acc11 = __builtin_amdgcn_mfma_f32_16x16x32_bf16(A1[ki], b1, acc11, 0, 0, 0);
        }
      }
    } else {
      const float *fa0, *fa1;
      if (ksl < 2) {
        const float* xb = p.x + ksl * 512 + quad * 8 + (size_t)t * HID;
        fa0 = xb + rm0 * (SEQ * HID);
        fa1 = xb + rm1 * (SEQ * HID);
      } else {
        const float* hr = (p.out + ((t & 1) ? 65536 : 0)) + (ksl - 2) * 512 + quad * 8;
        fa0 = hr + rm0 * HID;
        fa1 = hr + rm1 * HID;
      }
      #pragma unroll 2
      for (int ki = 0; ki < 16; ++ki) {
        bf16x8 a0 = cvt8(fa0 + ki * 32);
        bf16x8 a1 = cvt8(fa1 + ki * 32);
        bf16x8 b0 = *(const bf16x8*)(bB0 + ki * 32);
        bf16x8 b1 = *(const bf16x8*)(bB1 + ki * 32);
        acc00 = __builtin_amdgcn_mfma_f32_16x16x32_bf16(a0, b0, acc00, 0, 0, 0);
        acc01 = __builtin_amdgcn_mfma_f32_16x16x32_bf16(a0, b1, acc01, 0, 0, 0);
        acc10 = __builtin_amdgcn_mfma_f32_16x16x32_bf16(a1, b0, acc10, 0, 0, 0);
        acc11 = __builtin_amdgcn_mfma_f32_16x16x32_bf16(a1, b1, acc11, 0, 0, 0);
      }
    }

    // C layout: col = lane&15, row = quad*4 + reg (HW-verified round 3)
    {
      float* gp = gparts + ksl * (32 * GPS);
      #pragma unroll
      for (int r = 0; r < 4; ++r) {
        gp[(quad * 4 + r) * GPS + m16]           = acc00[r];
        gp[(quad * 4 + r) * GPS + 16 + m16]      = acc01[r];
        gp[(16 + quad * 4 + r) * GPS + m16]      = acc10[r];
        gp[(16 + quad * 4 + r) * GPS + 16 + m16] = acc11[r];
      }
    }
    __syncthreads();

    // ---- cell update: 32 rows x 4 col-pairs (128 threads) ----
    if (tid < 128) {
      int rl = tid >> 2, jp = tid & 3;
      f32x4 ga = {0,0,0,0}, gb = {0,0,0,0};
      #pragma unroll
      for (int s = 0; s < 4; ++s) {
        const float* gp = gparts + s * (32 * GPS) + rl * GPS + jp * 8;
        ga += *(const f32x4*)gp;
        gb += *(const f32x4*)(gp + 4);
      }
      f32x4 ba = *(const f32x4*)(bias_s + jp * 8);
      f32x4 bb = *(const f32x4*)(bias_s + jp * 8 + 4);

      float i0 = sig_(ga[0] + ba[0]);
      float f0 = sig_(ga[1] + ba[1]);
      float g0 = tanh_(ga[2] + ba[2]);
      float o0 = sig_(ga[3] + ba[3]);
      float i1 = sig_(gb[0] + bb[0]);
      float f1 = sig_(gb[1] + bb[1]);
      float g1 = tanh_(gb[2] + bb[2]);
      float o1 = sig_(gb[3] + bb[3]);

      int ci = rl * 8 + jp * 2;
      float c0 = f0 * cst[ci]     + i0 * g0;
      float c1 = f1 * cst[ci + 1] + i1 * g1;
      cst[ci] = c0; cst[ci + 1] = c1;
      float h0v = o0 * tanh_(c0);
      float h1v = o1 * tanh_(c1);

      size_t off = (size_t)(r0 + rl) * HID + j0 + jp * 2;
      if constexpr (FULL) {
        short* hw = (t & 1) ? p.hb0 : p.hb1;
        unsigned u = (unsigned)(unsigned short)f2b(h0v) |
                     ((unsigned)(unsigned short)f2b(h1v) << 16);
        // IF-coherent h store (sc1, compiler-tracked for syncthreads drain)
        __hip_atomic_store((unsigned*)(hw + off), u, __ATOMIC_RELAXED,
                           __HIP_MEMORY_SCOPE_AGENT);
        if (t == SEQ - 1) {
          f32x2 hv = {h0v, h1v}; *(f32x2*)(p.out + off) = hv;
          f32x2 cv = {c0, c1};   *(f32x2*)(p.out + 65536 + off) = cv;
        }
      } else {
        float* hw = p.out + ((t & 1) ? 0 : 65536);
        f32x2 hv = {h0v, h1v};
        *(f32x2*)(hw + off) = hv;
        if (t == SEQ - 1) { cfin0 = c0; cfin1 = c1; }
      }
    }

    if (t < SEQ - 1) {
      if constexpr (FULL) {
        // ---- fence-free barrier: all h traffic is already IF-coherent ----
        unsigned tgt = (unsigned)(t + 1);
        __syncthreads();   // drains the tracked sc1 h-stores (vmcnt) before arrive
        if (bid == 0) {
          if (tid != 0) {
            int polls = 0;
            while (__hip_atomic_load(&p.arrive[tid * 32], __ATOMIC_RELAXED,
                                     __HIP_MEMORY_SCOPE_AGENT) < tgt) {
              __builtin_amdgcn_s_sleep(2);
              if (++polls > (1 << 22)) break;
            }
          }
          __syncthreads();
          if (tid == 0)
            __hip_atomic_store(p.gen, tgt, __ATOMIC_RELAXED,
                               __HIP_MEMORY_SCOPE_AGENT);
          __syncthreads();
        } else {
          if (tid == 0) {
            __hip_atomic_store(&p.arrive[bid * 32], tgt, __ATOMIC_RELAXED,
                               __HIP_MEMORY_SCOPE_AGENT);
            int polls = 0;
            while (__hip_atomic_load(p.gen, __ATOMIC_RELAXED,
                                     __HIP_MEMORY_SCOPE_AGENT) < tgt) {
              __builtin_amdgcn_s_sleep(2);
              if (++polls > (1 << 22)) break;
            }
          }
          __syncthreads();
        }
      } else {
        gbar_fence(p.arrive, p.gen, tid, bid, (unsigned)(t + 1));
      }
    }
  }

  if constexpr (!FULL) {
    if (tid < 128) {
      int rl = tid >> 2, jp = tid & 3;
      size_t off = (size_t)(r0 + rl) * HID + j0 + jp * 2;
      f32x2 cv = {cfin0, cfin1};
      *(f32x2*)(p.out + 65536 + off) = cv;
    }
  }
}

extern "C" void kernel_launch(void* const* d_in, const int* in_sizes, int n_in,
                              void* d_out, int out_size, void* d_ws, size_t ws_size,
                              hipStream_t stream) {
  Params prm;
  prm.x = (const float*)d_in[0];
  for (int g = 0; g < 4; ++g) {
    prm.Wi[g] = (const float*)d_in[1 + g];
    prm.Wh[g] = (const float*)d_in[5 + g];
    prm.bi[g] = (const float*)d_in[9 + 2 * g];
    prm.bh[g] = (const float*)d_in[10 + 2 * g];
  }
  prm.out    = (float*)d_out;
  prm.arrive = (unsigned*)d_ws;
  prm.gen    = prm.arrive + 8192;          // own 128 B line after slot region
  prm.xbf = nullptr; prm.hb0 = nullptr; prm.hb1 = nullptr;

  const size_t need_full = 65536 + 67108864 + 2 * 131072;   // ~67.4 MB
  const bool full = ws_size >= need_full;
  if (full) {
    prm.xbf = (const short*)((char*)d_ws + 65536);
    prm.hb0 = (short*)((char*)d_ws + 65536 + 67108864);
    prm.hb1 = prm.hb0 + 65536;
  }

  const int smem_bytes = 131584 + 18432 + 1024 + 128;   // 151168
  hipFuncSetAttribute((const void*)lstm_persistent<true>,
                      hipFuncAttributeMaxDynamicSharedMemorySize, smem_bytes);
  hipFuncSetAttribute((const void*)lstm_persistent<false>,
                      hipFuncAttributeMaxDynamicSharedMemorySize, smem_bytes);

  if (full) {
    init_ws<<<256, 256, 0, stream>>>((unsigned*)d_ws, (unsigned*)prm.hb0, 32768);
    cvt_x<<<16384, 256, 0, stream>>>(prm.x, (short*)prm.xbf);
    lstm_persistent<true><<<NBLK, NTHR, smem_bytes, stream>>>(prm);
  } else {
    init_ws<<<256, 256, 0, stream>>>((unsigned*)d_ws, (unsigned*)d_out, 65536);
    lstm_persistent<false><<<NBLK, NTHR, smem_bytes, stream>>>(prm);
  }
}